// Round 1
// baseline (128.991 us; speedup 1.0000x reference)
//
#include <hip/hip_runtime.h>
#include <stdint.h>

#define N_PTS   512
#define N_NODES 10000
#define N_EDGES 50000
#define N_CMP   64
#define W64     784            // u64 words per bit-plane row; 784*64 = 50176 >= 50000
#define EBITS   (W64 * 64)     // 50176
#define BS_W64  160            // bitset u64 words per point; 160*64 = 10240 >= 10000
#define NCHUNK  8
#define CW      (W64 / NCHUNK) // 98
#define TN      8              // points per block in match kernel

// ---------------- Kernel A: learned-side bit planes ----------------
// tl[c,e] in {0..4}: index of the one-hot type. Encode 3 bit planes.
// e >= N_EDGES pad -> tl = 0 (code 000).
__global__ void build_L(const float* __restrict__ BL, uint64_t* __restrict__ Lp) {
    int c = blockIdx.y;
    int e = blockIdx.x * 256 + threadIdx.x;         // grid.x = 196 -> e in [0, 50176)
    int lane = threadIdx.x & 63;
    int tl = 0;
    if (e < N_EDGES) {
        size_t base = (size_t)c * (5 * N_EDGES) + e;
        float p1 = BL[base + 1 * N_EDGES];
        float p2 = BL[base + 2 * N_EDGES];
        float p3 = BL[base + 3 * N_EDGES];
        float p4 = BL[base + 4 * N_EDGES];
        tl = (p1 != 0.f ? 1 : 0) + (p2 != 0.f ? 2 : 0) + (p3 != 0.f ? 3 : 0) + (p4 != 0.f ? 4 : 0);
    }
    uint64_t b0 = __ballot(tl & 1);
    uint64_t b1 = __ballot(tl & 2);
    uint64_t b2 = __ballot(tl & 4);
    if (lane == 0) {
        int w = e >> 6;
        uint64_t* dst = Lp + ((size_t)c * W64 + w) * 3;
        dst[0] = b0; dst[1] = b1; dst[2] = b2;
    }
}

// ---------------- Kernel B0: per-point activation bitsets ----------------
__global__ void build_bitset(const int* __restrict__ act, uint64_t* __restrict__ bs) {
    int n = blockIdx.x;
    const int* row = act + (size_t)n * N_NODES;
    #pragma unroll 4
    for (int it = 0; it < 40; ++it) {               // 40*256 = 10240 bits = 160 words
        int i = it * 256 + threadIdx.x;
        int ic = i < N_NODES ? i : N_NODES - 1;
        int pred = (i < N_NODES) && (row[ic] != 0);
        uint64_t m = __ballot(pred);
        if ((threadIdx.x & 63) == 0) bs[(size_t)n * BS_W64 + (i >> 6)] = m;
    }
}

// ---------------- Kernel B: point-side bit planes (q = 2a+b+1, pad=7) ----------------
// 4 points per block share one pass over an edge chunk. grid = (4 chunks, 128 groups)
__global__ void build_Q(const uint64_t* __restrict__ bs, const int2* __restrict__ edges,
                        uint64_t* __restrict__ Qp) {
    __shared__ uint32_t lbs[4][BS_W64 * 2];         // 4 x 320 u32 bitsets
    int n0 = blockIdx.y * 4;
    const uint32_t* src = (const uint32_t*)(bs + (size_t)n0 * BS_W64);
    for (int idx = threadIdx.x; idx < 4 * BS_W64 * 2; idx += 256)
        ((uint32_t*)lbs)[idx] = src[idx];
    __syncthreads();

    int lane = threadIdx.x & 63;
    int ebase = blockIdx.x * (EBITS / 4);           // 12544-edge chunk
    for (int it = 0; it < (EBITS / 4) / 256; ++it) {// 49 iters
        int e = ebase + it * 256 + threadIdx.x;
        int ec = e < N_EDGES ? e : 0;
        int2 ei = edges[ec];
        int valid = e < N_EDGES;
        int w = e >> 6;                             // lane0's value is the wave's word idx
        #pragma unroll
        for (int p = 0; p < 4; ++p) {
            int a = (lbs[p][ei.x >> 5] >> (ei.x & 31)) & 1;
            int b = (lbs[p][ei.y >> 5] >> (ei.y & 31)) & 1;
            int q = valid ? (2 * a + b + 1) : 7;
            uint64_t b0 = __ballot(q & 1);
            uint64_t b1 = __ballot(q & 2);
            uint64_t b2 = __ballot(q & 4);
            if (lane == 0) {
                uint64_t* dst = Qp + ((size_t)(n0 + p) * W64 + w) * 3;
                dst[0] = b0; dst[1] = b1; dst[2] = b2;
            }
        }
    }
}

// ---------------- Kernel C: mismatch popcount ----------------
// Block: TN=8 points x 64 cmps x one e-chunk of CW u64 words.
// Q chunk staged in LDS; L streamed (L2-resident, 1.2 MB total).
// Thread owns 2 (n,c) pairs with the SAME c -> L loads shared.
__global__ void match_count(const uint64_t* __restrict__ Lp, const uint64_t* __restrict__ Qp,
                            int* __restrict__ part) {
    __shared__ uint64_t qs[TN * CW * 3];            // 2352 u64 = 18.4 KB
    int chunk = blockIdx.x;                         // 0..7
    int n0 = blockIdx.y * TN;                       // 0..504
    for (int idx = threadIdx.x; idx < TN * CW * 3; idx += 256) {
        int p = idx / (CW * 3);
        int r = idx - p * (CW * 3);
        qs[idx] = Qp[((size_t)(n0 + p) * W64 + chunk * CW) * 3 + r];
    }
    __syncthreads();

    int c   = threadIdx.x & 63;
    int nl0 = threadIdx.x >> 6;                     // 0..3
    const uint64_t* lrow = Lp + ((size_t)c * W64 + chunk * CW) * 3;
    const uint64_t* q0 = qs + nl0 * (CW * 3);
    const uint64_t* q1 = qs + (nl0 + 4) * (CW * 3);
    int cnt0 = 0, cnt1 = 0;
    for (int w = 0; w < CW; ++w) {
        uint64_t l0 = lrow[w * 3 + 0], l1 = lrow[w * 3 + 1], l2 = lrow[w * 3 + 2];
        uint64_t a0 = q0[w * 3 + 0],   a1 = q0[w * 3 + 1],   a2 = q0[w * 3 + 2];
        cnt0 += __popcll((l0 ^ a0) | (l1 ^ a1) | (l2 ^ a2));
        uint64_t b0 = q1[w * 3 + 0],   b1 = q1[w * 3 + 1],   b2 = q1[w * 3 + 2];
        cnt1 += __popcll((l0 ^ b0) | (l1 ^ b1) | (l2 ^ b2));
    }
    part[((size_t)chunk * N_PTS + n0 + nl0)     * N_CMP + c] = cnt0;
    part[((size_t)chunk * N_PTS + n0 + nl0 + 4) * N_CMP + c] = cnt1;
}

// ---------------- Kernel D1: sum chunks, matches = EBITS - mismatches, block min ----------------
__global__ void reduce1(const int* __restrict__ part, int* __restrict__ energy,
                        int* __restrict__ blockmin) {
    int t = blockIdx.x * 256 + threadIdx.x;         // 0..32767
    int s = 0;
    #pragma unroll
    for (int ch = 0; ch < NCHUNK; ++ch) s += part[ch * (N_PTS * N_CMP) + t];
    int e = EBITS - s;
    energy[t] = e;
    int m = e;
    for (int off = 32; off; off >>= 1) m = min(m, __shfl_down(m, off, 64));
    __shared__ int wm[4];
    if ((threadIdx.x & 63) == 0) wm[threadIdx.x >> 6] = m;
    __syncthreads();
    if (threadIdx.x == 0) blockmin[blockIdx.x] = min(min(wm[0], wm[1]), min(wm[2], wm[3]));
}

// ---------------- Kernel D2: global min + subtract ----------------
__global__ void finalize(const int* __restrict__ energy, const int* __restrict__ blockmin,
                         float* __restrict__ out) {
    __shared__ int wm[4];
    __shared__ int mshared;
    int m = 0x7fffffff;
    for (int i = threadIdx.x; i < 128; i += 256) m = min(m, blockmin[i]);
    for (int off = 32; off; off >>= 1) m = min(m, __shfl_down(m, off, 64));
    if ((threadIdx.x & 63) == 0) wm[threadIdx.x >> 6] = m;
    __syncthreads();
    if (threadIdx.x == 0) mshared = min(min(wm[0], wm[1]), min(wm[2], wm[3]));
    __syncthreads();
    int mv = mshared;
    for (int t = threadIdx.x; t < N_PTS * N_CMP; t += 256)
        out[t] = (float)(energy[t] - mv);
}

extern "C" void kernel_launch(void* const* d_in, const int* in_sizes, int n_in,
                              void* d_out, int out_size, void* d_ws, size_t ws_size,
                              hipStream_t stream) {
    const int*   act   = (const int*)d_in[0];       // 512 x 10000
    const float* BL    = (const float*)d_in[1];     // 64 x 250000
    const int2*  edges = (const int2*)d_in[2];      // 50000 x 2
    float* out = (float*)d_out;

    uint64_t* Lp = (uint64_t*)d_ws;                             // 64*784*3   u64 = 1.20 MB
    uint64_t* Qp = Lp + (size_t)N_CMP * W64 * 3;                // 512*784*3  u64 = 9.63 MB
    uint64_t* bs = Qp + (size_t)N_PTS * W64 * 3;                // 512*160    u64 = 0.66 MB
    int* part     = (int*)(bs + (size_t)N_PTS * BS_W64);        // 8*512*64   int = 1.05 MB
    int* energy   = part + NCHUNK * N_PTS * N_CMP;              // 32768 int
    int* blockmin = energy + N_PTS * N_CMP;                     // 128 int

    build_L     <<<dim3(EBITS / 256, N_CMP), 256, 0, stream>>>(BL, Lp);
    build_bitset<<<N_PTS, 256, 0, stream>>>(act, bs);
    build_Q     <<<dim3(4, N_PTS / 4), 256, 0, stream>>>(bs, edges, Qp);
    match_count <<<dim3(NCHUNK, N_PTS / TN), 256, 0, stream>>>(Lp, Qp, part);
    reduce1     <<<N_PTS * N_CMP / 256, 256, 0, stream>>>(part, energy, blockmin);
    finalize    <<<1, 256, 0, stream>>>(energy, blockmin, out);
}

// Round 2
// 118.504 us; speedup vs baseline: 1.0885x; 1.0885x over previous
//
#include <hip/hip_runtime.h>
#include <stdint.h>

#define N_PTS   512
#define N_NODES 10000
#define N_EDGES 50000
#define N_CMP   64
#define W64     784             // u64 words per bit-plane row; 784*64 = 50176
#define EBITS   (W64 * 64)      // 50176
#define LSTRIDE (N_CMP * W64)   // per-plane stride, L
#define QSTRIDE (N_PTS * W64)   // per-plane stride, Q
#define BS_W32  320             // u32 words per point bitset; 320*32 = 10240 >= 10000
#define QCH     28              // edge chunks in build_Q: 50176/28 = 1792 = 7*256
#define NCHUNK  14
#define CW      (W64 / NCHUNK)  // 56
#define TN      8               // points per block in match kernel

typedef unsigned long long u64;
typedef u64 u64v2 __attribute__((ext_vector_type(2)));

// ---------------- Kernel A: learned-side bit planes (planar layout) ----------------
// tl[c,e] in {0..4}; pad (e>=N_EDGES) -> 000. Planes: L[plane][c][w].
__global__ void build_L(const float* __restrict__ BL, u64* __restrict__ Lp) {
    int c = blockIdx.y;
    int e = blockIdx.x * 256 + threadIdx.x;
    int lane = threadIdx.x & 63;
    int tl = 0;
    if (e < N_EDGES) {
        size_t base = (size_t)c * (5 * N_EDGES) + e;
        float p1 = BL[base + 1 * N_EDGES];
        float p2 = BL[base + 2 * N_EDGES];
        float p3 = BL[base + 3 * N_EDGES];
        float p4 = BL[base + 4 * N_EDGES];
        tl = (p1 != 0.f ? 1 : 0) + (p2 != 0.f ? 2 : 0) + (p3 != 0.f ? 3 : 0) + (p4 != 0.f ? 4 : 0);
    }
    u64 b0 = __ballot(tl & 1);
    u64 b1 = __ballot(tl & 2);
    u64 b2 = __ballot(tl & 4);
    if (lane == 0) {
        size_t o = (size_t)c * W64 + (e >> 6);
        Lp[o] = b0; Lp[LSTRIDE + o] = b1; Lp[2 * LSTRIDE + o] = b2;
    }
}

// ---------------- Kernel B0: per-point activation bitsets, 4-point interleaved ----------------
// bs4[group][w32][p] u32 ; group = n>>2, p = n&3
__global__ void build_bitset(const int* __restrict__ act, uint32_t* __restrict__ bs4) {
    int n = blockIdx.x;
    const int* row = act + (size_t)n * N_NODES;
    uint32_t* base = bs4 + (size_t)(n >> 2) * (BS_W32 * 4) + (n & 3);
    #pragma unroll 4
    for (int it = 0; it < 40; ++it) {               // 40*256 = 10240 bits
        int i = it * 256 + threadIdx.x;
        int ic = i < N_NODES ? i : N_NODES - 1;
        int pred = (i < N_NODES) && (row[ic] != 0);
        u64 m = __ballot(pred);
        if ((threadIdx.x & 63) == 0) {
            int w64 = i >> 6;
            base[(2 * w64) * 4]     = (uint32_t)m;
            base[(2 * w64 + 1) * 4] = (uint32_t)(m >> 32);
        }
    }
}

// ---------------- Kernel B: point-side bit planes ----------------
// q = 2a+b+1: bit0 = ~B, bit1 = A^B, bit2 = A&B; pad bits -> 111.
// One ds_read_b128 per node fetches all 4 points' bits.
__global__ void build_Q(const uint32_t* __restrict__ bs4, const int2* __restrict__ edges,
                        u64* __restrict__ Qp) {
    __shared__ uint4 lbs[BS_W32];                   // 5 KB: [w32][4 points]
    int n0 = blockIdx.y * 4;
    const uint4* src = (const uint4*)(bs4 + (size_t)blockIdx.y * (BS_W32 * 4));
    for (int idx = threadIdx.x; idx < BS_W32; idx += 256) lbs[idx] = src[idx];
    __syncthreads();

    int lane = threadIdx.x & 63;
    int ebase = blockIdx.x * (EBITS / QCH);         // 1792-edge chunk
    for (int it = 0; it < (EBITS / QCH) / 256; ++it) {  // 7 iters
        int e = ebase + it * 256 + threadIdx.x;
        int ec = e < N_EDGES ? e : N_EDGES - 1;
        int2 ei = edges[ec];
        uint4 wa = lbs[ei.x >> 5];
        uint4 wb = lbs[ei.y >> 5];
        int sx = ei.x & 31, sy = ei.y & 31;
        u64 A0 = __ballot((wa.x >> sx) & 1), B0 = __ballot((wb.x >> sy) & 1);
        u64 A1 = __ballot((wa.y >> sx) & 1), B1 = __ballot((wb.y >> sy) & 1);
        u64 A2 = __ballot((wa.z >> sx) & 1), B2 = __ballot((wb.z >> sy) & 1);
        u64 A3 = __ballot((wa.w >> sx) & 1), B3 = __ballot((wb.w >> sy) & 1);
        if (lane == 0) {
            int ww = (ebase + it * 256 + (threadIdx.x & 192)) >> 6; // wave's word index
            u64 pad = ww < 781 ? 0ULL : (ww == 781 ? 0xFFFFFFFFFFFF0000ULL : ~0ULL);
            size_t o = (size_t)n0 * W64 + ww;
            Qp[o]               = (~B0) | pad;
            Qp[QSTRIDE + o]     = (A0 ^ B0) | pad;
            Qp[2 * QSTRIDE + o] = (A0 & B0) | pad;
            o += W64;
            Qp[o]               = (~B1) | pad;
            Qp[QSTRIDE + o]     = (A1 ^ B1) | pad;
            Qp[2 * QSTRIDE + o] = (A1 & B1) | pad;
            o += W64;
            Qp[o]               = (~B2) | pad;
            Qp[QSTRIDE + o]     = (A2 ^ B2) | pad;
            Qp[2 * QSTRIDE + o] = (A2 & B2) | pad;
            o += W64;
            Qp[o]               = (~B3) | pad;
            Qp[QSTRIDE + o]     = (A3 ^ B3) | pad;
            Qp[2 * QSTRIDE + o] = (A3 & B3) | pad;
        }
    }
}

// ---------------- Kernel C: mismatch popcount ----------------
__global__ void match_count(const u64* __restrict__ Lp, const u64* __restrict__ Qp,
                            int* __restrict__ part) {
    __shared__ u64 qs[3][TN][CW];                   // 10.5 KB
    int chunk = blockIdx.x;                         // 0..13
    int n0 = blockIdx.y * TN;
    for (int idx = threadIdx.x; idx < 3 * TN * CW; idx += 256) {
        int pl = idx / (TN * CW);
        int r  = idx - pl * (TN * CW);
        int p  = r / CW, w = r - p * CW;
        qs[pl][p][w] = Qp[(size_t)pl * QSTRIDE + (size_t)(n0 + p) * W64 + chunk * CW + w];
    }
    __syncthreads();

    int c  = threadIdx.x & 63;
    int nl = threadIdx.x >> 6;                      // 0..3
    size_t lo = (size_t)c * W64 + chunk * CW;
    const u64* L0 = Lp + lo;
    const u64* L1 = Lp + LSTRIDE + lo;
    const u64* L2 = Lp + 2 * LSTRIDE + lo;
    const u64* qa0 = &qs[0][nl][0], *qa1 = &qs[1][nl][0], *qa2 = &qs[2][nl][0];
    const u64* qb0 = &qs[0][nl + 4][0], *qb1 = &qs[1][nl + 4][0], *qb2 = &qs[2][nl + 4][0];
    int cnt0 = 0, cnt1 = 0;
    for (int w = 0; w < CW; w += 2) {
        u64v2 l0 = *(const u64v2*)(L0 + w);
        u64v2 l1 = *(const u64v2*)(L1 + w);
        u64v2 l2 = *(const u64v2*)(L2 + w);
        u64v2 a0 = *(const u64v2*)(qa0 + w);
        u64v2 a1 = *(const u64v2*)(qa1 + w);
        u64v2 a2 = *(const u64v2*)(qa2 + w);
        cnt0 += __popcll((l0.x ^ a0.x) | (l1.x ^ a1.x) | (l2.x ^ a2.x));
        cnt0 += __popcll((l0.y ^ a0.y) | (l1.y ^ a1.y) | (l2.y ^ a2.y));
        u64v2 b0 = *(const u64v2*)(qb0 + w);
        u64v2 b1 = *(const u64v2*)(qb1 + w);
        u64v2 b2 = *(const u64v2*)(qb2 + w);
        cnt1 += __popcll((l0.x ^ b0.x) | (l1.x ^ b1.x) | (l2.x ^ b2.x));
        cnt1 += __popcll((l0.y ^ b0.y) | (l1.y ^ b1.y) | (l2.y ^ b2.y));
    }
    part[((size_t)chunk * N_PTS + n0 + nl) * N_CMP + c]     = cnt0;
    part[((size_t)chunk * N_PTS + n0 + nl + 4) * N_CMP + c] = cnt1;
}

// ---------------- Kernel D1: sum chunks, energy = EBITS - mismatches, block min ----------------
__global__ void reduce1(const int* __restrict__ part, int* __restrict__ energy,
                        int* __restrict__ blockmin) {
    int t = blockIdx.x * 256 + threadIdx.x;
    int s = 0;
    #pragma unroll
    for (int ch = 0; ch < NCHUNK; ++ch) s += part[ch * (N_PTS * N_CMP) + t];
    int e = EBITS - s;
    energy[t] = e;
    int m = e;
    for (int off = 32; off; off >>= 1) m = min(m, __shfl_down(m, off, 64));
    __shared__ int wm[4];
    if ((threadIdx.x & 63) == 0) wm[threadIdx.x >> 6] = m;
    __syncthreads();
    if (threadIdx.x == 0) blockmin[blockIdx.x] = min(min(wm[0], wm[1]), min(wm[2], wm[3]));
}

// ---------------- Kernel D2: global min ----------------
__global__ void gmin_k(const int* __restrict__ blockmin, int* __restrict__ gmin) {
    int m = blockmin[threadIdx.x];                  // 128 threads
    for (int off = 32; off; off >>= 1) m = min(m, __shfl_down(m, off, 64));
    __shared__ int wm[2];
    if ((threadIdx.x & 63) == 0) wm[threadIdx.x >> 6] = m;
    __syncthreads();
    if (threadIdx.x == 0) gmin[0] = min(wm[0], wm[1]);
}

// ---------------- Kernel D3: subtract + convert ----------------
__global__ void subk(const int* __restrict__ energy, const int* __restrict__ gmin,
                     float* __restrict__ out) {
    int i = blockIdx.x * 256 + threadIdx.x;         // 32 blocks: 8192 int4
    int mv = gmin[0];
    int4 e = ((const int4*)energy)[i];
    float4 o = make_float4((float)(e.x - mv), (float)(e.y - mv),
                           (float)(e.z - mv), (float)(e.w - mv));
    ((float4*)out)[i] = o;
}

extern "C" void kernel_launch(void* const* d_in, const int* in_sizes, int n_in,
                              void* d_out, int out_size, void* d_ws, size_t ws_size,
                              hipStream_t stream) {
    const int*   act   = (const int*)d_in[0];       // 512 x 10000
    const float* BL    = (const float*)d_in[1];     // 64 x 250000
    const int2*  edges = (const int2*)d_in[2];      // 50000 x 2
    float* out = (float*)d_out;

    u64* Lp = (u64*)d_ws;                           // 3*64*784  u64 = 1.20 MB
    u64* Qp = Lp + 3 * LSTRIDE;                     // 3*512*784 u64 = 9.63 MB
    char* r3 = (char*)(Qp + 3 * (size_t)QSTRIDE);
    uint32_t* bs4 = (uint32_t*)r3;                  // 128*320*4 u32 = 0.66 MB (dead after build_Q)
    int* part     = (int*)r3;                       // aliases bs4; 14*32768 int = 1.83 MB
    int* energy   = part + NCHUNK * N_PTS * N_CMP;  // 32768 int
    int* blockmin = energy + N_PTS * N_CMP;         // 128 int
    int* gmin     = blockmin + 128;                 // 1 int

    build_L     <<<dim3(EBITS / 256, N_CMP), 256, 0, stream>>>(BL, Lp);
    build_bitset<<<N_PTS, 256, 0, stream>>>(act, bs4);
    build_Q     <<<dim3(QCH, N_PTS / 4), 256, 0, stream>>>(bs4, edges, Qp);
    match_count <<<dim3(NCHUNK, N_PTS / TN), 256, 0, stream>>>(Lp, Qp, part);
    reduce1     <<<N_PTS * N_CMP / 256, 256, 0, stream>>>(part, energy, blockmin);
    gmin_k      <<<1, 128, 0, stream>>>(blockmin, gmin);
    subk        <<<N_PTS * N_CMP / 1024, 256, 0, stream>>>(energy, gmin, out);
}

// Round 3
// 93.873 us; speedup vs baseline: 1.3741x; 1.2624x over previous
//
#include <hip/hip_runtime.h>
#include <stdint.h>

#define N_PTS   512
#define N_NODES 10000
#define N_EDGES 50000
#define N_CMP   64
#define W64     784             // u64 words per bit-plane row; 784*64 = 50176
#define EBITS   (W64 * 64)      // 50176
#define LSTRIDE (N_CMP * W64)   // per-plane stride, L
#define QSTRIDE (N_PTS * W64)   // per-plane stride, Q
#define BS_W32  320             // u32 words per point bitset; 320*32 = 10240 >= 10000
#define QCH     28              // edge chunks in build_Q
#define NCHUNK  28
#define CW      (W64 / NCHUNK)  // 28
#define TN      16              // points per block in match kernel

typedef unsigned long long u64;
typedef u64 u64v2 __attribute__((ext_vector_type(2)));

// ---------------- Kernel A: learned-side bit planes (planar layout) ----------------
__global__ void build_L(const float* __restrict__ BL, u64* __restrict__ Lp) {
    int c = blockIdx.y;
    int e = blockIdx.x * 256 + threadIdx.x;
    int lane = threadIdx.x & 63;
    int tl = 0;
    if (e < N_EDGES) {
        size_t base = (size_t)c * (5 * N_EDGES) + e;
        float p1 = BL[base + 1 * N_EDGES];
        float p2 = BL[base + 2 * N_EDGES];
        float p3 = BL[base + 3 * N_EDGES];
        float p4 = BL[base + 4 * N_EDGES];
        tl = (p1 != 0.f ? 1 : 0) + (p2 != 0.f ? 2 : 0) + (p3 != 0.f ? 3 : 0) + (p4 != 0.f ? 4 : 0);
    }
    u64 b0 = __ballot(tl & 1);
    u64 b1 = __ballot(tl & 2);
    u64 b2 = __ballot(tl & 4);
    if (lane == 0) {
        size_t o = (size_t)c * W64 + (e >> 6);
        Lp[o] = b0; Lp[LSTRIDE + o] = b1; Lp[2 * LSTRIDE + o] = b2;
    }
}

// ---------------- Kernel B0: per-point activation bitsets, 4-point interleaved ----------------
__global__ void build_bitset(const int* __restrict__ act, uint32_t* __restrict__ bs4) {
    int n = blockIdx.x;
    const int* row = act + (size_t)n * N_NODES;
    uint32_t* base = bs4 + (size_t)(n >> 2) * (BS_W32 * 4) + (n & 3);
    #pragma unroll 4
    for (int it = 0; it < 40; ++it) {
        int i = it * 256 + threadIdx.x;
        int ic = i < N_NODES ? i : N_NODES - 1;
        int pred = (i < N_NODES) && (row[ic] != 0);
        u64 m = __ballot(pred);
        if ((threadIdx.x & 63) == 0) {
            int w64 = i >> 6;
            base[(2 * w64) * 4]     = (uint32_t)m;
            base[(2 * w64 + 1) * 4] = (uint32_t)(m >> 32);
        }
    }
}

// ---------------- Kernel B: point-side bit planes ----------------
// q = 2a+b+1: bit0 = ~B, bit1 = A^B, bit2 = A&B; pad bits -> 111.
__global__ void build_Q(const uint32_t* __restrict__ bs4, const int2* __restrict__ edges,
                        u64* __restrict__ Qp) {
    __shared__ uint4 lbs[BS_W32];                   // 5 KB
    int n0 = blockIdx.y * 4;
    const uint4* src = (const uint4*)(bs4 + (size_t)blockIdx.y * (BS_W32 * 4));
    for (int idx = threadIdx.x; idx < BS_W32; idx += 256) lbs[idx] = src[idx];
    __syncthreads();

    int lane = threadIdx.x & 63;
    int ebase = blockIdx.x * (EBITS / QCH);
    for (int it = 0; it < (EBITS / QCH) / 256; ++it) {
        int e = ebase + it * 256 + threadIdx.x;
        int ec = e < N_EDGES ? e : N_EDGES - 1;
        int2 ei = edges[ec];
        uint4 wa = lbs[ei.x >> 5];
        uint4 wb = lbs[ei.y >> 5];
        int sx = ei.x & 31, sy = ei.y & 31;
        u64 A0 = __ballot((wa.x >> sx) & 1), B0 = __ballot((wb.x >> sy) & 1);
        u64 A1 = __ballot((wa.y >> sx) & 1), B1 = __ballot((wb.y >> sy) & 1);
        u64 A2 = __ballot((wa.z >> sx) & 1), B2 = __ballot((wb.z >> sy) & 1);
        u64 A3 = __ballot((wa.w >> sx) & 1), B3 = __ballot((wb.w >> sy) & 1);
        if (lane == 0) {
            int ww = (ebase + it * 256 + (threadIdx.x & 192)) >> 6;
            u64 pad = ww < 781 ? 0ULL : (ww == 781 ? 0xFFFFFFFFFFFF0000ULL : ~0ULL);
            size_t o = (size_t)n0 * W64 + ww;
            Qp[o]               = (~B0) | pad;
            Qp[QSTRIDE + o]     = (A0 ^ B0) | pad;
            Qp[2 * QSTRIDE + o] = (A0 & B0) | pad;
            o += W64;
            Qp[o]               = (~B1) | pad;
            Qp[QSTRIDE + o]     = (A1 ^ B1) | pad;
            Qp[2 * QSTRIDE + o] = (A1 & B1) | pad;
            o += W64;
            Qp[o]               = (~B2) | pad;
            Qp[QSTRIDE + o]     = (A2 ^ B2) | pad;
            Qp[2 * QSTRIDE + o] = (A2 & B2) | pad;
            o += W64;
            Qp[o]               = (~B3) | pad;
            Qp[QSTRIDE + o]     = (A3 ^ B3) | pad;
            Qp[2 * QSTRIDE + o] = (A3 & B3) | pad;
        }
    }
}

// ---------------- Kernel C: mismatch popcount, LDS-staged both sides ----------------
// Block: 512 threads = (c 0..63) x (nl 0..7); TN=16 points, 2 per thread.
// L staged TRANSPOSED: Ll[plane][w][c] -> compute reads lanes=c conflict-free.
__global__ void __launch_bounds__(512, 2)
match_count(const u64* __restrict__ Lp, const u64* __restrict__ Qp,
            int* __restrict__ part) {
    __shared__ u64 Ll[3][CW][64];                   // 43 KB
    __shared__ u64 qsh[3][TN][CW];                  // 10.5 KB
    int chunk = blockIdx.x;                         // 0..27
    int n0 = blockIdx.y * TN;
    int t = threadIdx.x;
    int cw0 = chunk * CW;

    if (t < 384) {                                  // L: 192 rows (plane,c), half-rows of 14
        int r = t >> 1, h = t & 1;
        int plane = r >> 6, c = r & 63;
        const u64* src = Lp + (size_t)plane * LSTRIDE + (size_t)c * W64 + cw0 + h * 14;
        #pragma unroll
        for (int j = 0; j < 14; ++j) Ll[plane][h * 14 + j][c] = src[j];
    } else {                                        // Q: 1344 u64 linear, coalesced
        int u = t - 384;
        #pragma unroll
        for (int k = 0; k < 11; ++k) {
            int idx = k * 128 + u;
            if (idx < 3 * TN * CW) {
                int plane = idx / (TN * CW);
                int rest = idx - plane * (TN * CW);
                int n = rest / CW, w = rest - n * CW;
                qsh[plane][n][w] = Qp[(size_t)plane * QSTRIDE + (size_t)(n0 + n) * W64 + cw0 + w];
            }
        }
    }
    __syncthreads();

    int c  = t & 63;
    int nl = t >> 6;                                // 0..7
    int cnt0 = 0, cnt1 = 0;
    #pragma unroll
    for (int w = 0; w < CW; w += 2) {
        u64 l0a = Ll[0][w][c], l0b = Ll[0][w + 1][c];
        u64 l1a = Ll[1][w][c], l1b = Ll[1][w + 1][c];
        u64 l2a = Ll[2][w][c], l2b = Ll[2][w + 1][c];
        u64v2 a0 = *(const u64v2*)&qsh[0][nl][w];
        u64v2 a1 = *(const u64v2*)&qsh[1][nl][w];
        u64v2 a2 = *(const u64v2*)&qsh[2][nl][w];
        cnt0 += __popcll((l0a ^ a0.x) | (l1a ^ a1.x) | (l2a ^ a2.x));
        cnt0 += __popcll((l0b ^ a0.y) | (l1b ^ a1.y) | (l2b ^ a2.y));
        u64v2 b0 = *(const u64v2*)&qsh[0][nl + 8][w];
        u64v2 b1 = *(const u64v2*)&qsh[1][nl + 8][w];
        u64v2 b2 = *(const u64v2*)&qsh[2][nl + 8][w];
        cnt1 += __popcll((l0a ^ b0.x) | (l1a ^ b1.x) | (l2a ^ b2.x));
        cnt1 += __popcll((l0b ^ b0.y) | (l1b ^ b1.y) | (l2b ^ b2.y));
    }
    part[((size_t)chunk * N_PTS + n0 + nl) * N_CMP + c]     = cnt0;
    part[((size_t)chunk * N_PTS + n0 + nl + 8) * N_CMP + c] = cnt1;
}

// ---------------- Kernel D1: sum chunks, energy = EBITS - mismatches, block min ----------------
__global__ void reduce1(const int* __restrict__ part, int* __restrict__ energy,
                        int* __restrict__ blockmin) {
    int t = blockIdx.x * 256 + threadIdx.x;
    int s = 0;
    #pragma unroll
    for (int ch = 0; ch < NCHUNK; ++ch) s += part[ch * (N_PTS * N_CMP) + t];
    int e = EBITS - s;
    energy[t] = e;
    int m = e;
    for (int off = 32; off; off >>= 1) m = min(m, __shfl_down(m, off, 64));
    __shared__ int wm[4];
    if ((threadIdx.x & 63) == 0) wm[threadIdx.x >> 6] = m;
    __syncthreads();
    if (threadIdx.x == 0) blockmin[blockIdx.x] = min(min(wm[0], wm[1]), min(wm[2], wm[3]));
}

// ---------------- Kernel D2: global min (redone per block) + subtract ----------------
__global__ void subk(const int* __restrict__ energy, const int* __restrict__ blockmin,
                     float* __restrict__ out) {
    __shared__ int wm[4];
    __shared__ int ms;
    int t = threadIdx.x;
    int m = t < 128 ? blockmin[t] : 0x7fffffff;
    for (int off = 32; off; off >>= 1) m = min(m, __shfl_down(m, off, 64));
    if ((t & 63) == 0) wm[t >> 6] = m;
    __syncthreads();
    if (t == 0) ms = min(wm[0], wm[1]);
    __syncthreads();
    int mv = ms;
    int i = blockIdx.x * 256 + t;
    int4 e = ((const int4*)energy)[i];
    ((float4*)out)[i] = make_float4((float)(e.x - mv), (float)(e.y - mv),
                                    (float)(e.z - mv), (float)(e.w - mv));
}

extern "C" void kernel_launch(void* const* d_in, const int* in_sizes, int n_in,
                              void* d_out, int out_size, void* d_ws, size_t ws_size,
                              hipStream_t stream) {
    const int*   act   = (const int*)d_in[0];       // 512 x 10000
    const float* BL    = (const float*)d_in[1];     // 64 x 250000
    const int2*  edges = (const int2*)d_in[2];      // 50000 x 2
    float* out = (float*)d_out;

    u64* Lp = (u64*)d_ws;                           // 3*64*784  u64 = 1.20 MB
    u64* Qp = Lp + 3 * (size_t)LSTRIDE;             // 3*512*784 u64 = 9.63 MB
    char* r3 = (char*)(Qp + 3 * (size_t)QSTRIDE);
    uint32_t* bs4 = (uint32_t*)r3;                  // 0.66 MB (dead after build_Q)
    int* part     = (int*)r3;                       // aliases bs4; 28*32768*4 = 3.67 MB
    int* energy   = part + NCHUNK * N_PTS * N_CMP;  // 32768 int
    int* blockmin = energy + N_PTS * N_CMP;         // 128 int

    build_L     <<<dim3(EBITS / 256, N_CMP), 256, 0, stream>>>(BL, Lp);
    build_bitset<<<N_PTS, 256, 0, stream>>>(act, bs4);
    build_Q     <<<dim3(QCH, N_PTS / 4), 256, 0, stream>>>(bs4, edges, Qp);
    match_count <<<dim3(NCHUNK, N_PTS / TN), 512, 0, stream>>>(Lp, Qp, part);
    reduce1     <<<N_PTS * N_CMP / 256, 256, 0, stream>>>(part, energy, blockmin);
    subk        <<<N_PTS * N_CMP / 1024, 256, 0, stream>>>(energy, blockmin, out);
}

// Round 4
// 76.874 us; speedup vs baseline: 1.6779x; 1.2211x over previous
//
#include <hip/hip_runtime.h>
#include <stdint.h>

#define N_PTS   512
#define N_NODES 10000
#define N_EDGES 50000
#define N_CMP   64
#define W64     784             // u64 words per bit-plane row; 784*64 = 50176
#define EBITS   (W64 * 64)      // 50176
#define LSTRIDE (N_CMP * W64)   // per-plane stride, L
#define BS_W64  160             // u64 words per point bitset; 160*64 = 10240 >= 10000
#define NCHUNK  28
#define CW      (W64 / NCHUNK)  // 28 words = 1792 edges per chunk
#define TN      16              // points per block in fused kernel

typedef unsigned long long u64;
typedef u64 u64v2 __attribute__((ext_vector_type(2)));

// ---------------- Kernel A: learned-side bit planes (planar layout) ----------------
// tl[c,e] in {0..4}; pad (e>=N_EDGES) -> 000. Planes: Lp[plane][c][w].
__global__ void build_L(const float* __restrict__ BL, u64* __restrict__ Lp) {
    int c = blockIdx.y;
    int e = blockIdx.x * 256 + threadIdx.x;
    int lane = threadIdx.x & 63;
    int tl = 0;
    if (e < N_EDGES) {
        size_t base = (size_t)c * (5 * N_EDGES) + e;
        float p1 = BL[base + 1 * N_EDGES];
        float p2 = BL[base + 2 * N_EDGES];
        float p3 = BL[base + 3 * N_EDGES];
        float p4 = BL[base + 4 * N_EDGES];
        tl = (p1 != 0.f ? 1 : 0) + (p2 != 0.f ? 2 : 0) + (p3 != 0.f ? 3 : 0) + (p4 != 0.f ? 4 : 0);
    }
    u64 b0 = __ballot(tl & 1);
    u64 b1 = __ballot(tl & 2);
    u64 b2 = __ballot(tl & 4);
    if (lane == 0) {
        size_t o = (size_t)c * W64 + (e >> 6);
        Lp[o] = b0; Lp[LSTRIDE + o] = b1; Lp[2 * LSTRIDE + o] = b2;
    }
}

// ---------------- Kernel B0: per-point activation bitsets (plain u64 rows) ----------------
__global__ void build_bitset(const int* __restrict__ act, u64* __restrict__ bs) {
    int n = blockIdx.x;
    const int* row = act + (size_t)n * N_NODES;
    #pragma unroll 4
    for (int it = 0; it < 40; ++it) {               // 40*256 = 10240 bits = 160 words
        int i = it * 256 + threadIdx.x;
        int ic = i < N_NODES ? i : N_NODES - 1;
        int pred = (i < N_NODES) && (row[ic] != 0);
        u64 m = __ballot(pred);
        if ((threadIdx.x & 63) == 0) bs[(size_t)n * BS_W64 + (i >> 6)] = m;
    }
}

// ---------------- Kernel C (fused): Q-plane build + mismatch popcount ----------------
// Block (chunk, ngroup): 512 threads = 8 waves. TN=16 points, CW=28 words.
// Phase 1: stage L transposed (coalesced reads), stage 16 point-bitsets.
// Phase 2: ballot-build Q planes into LDS (q=2a+b+1: ~B, A^B, A&B; pad->111).
// Phase 3: popcount mismatches; thread (c,nl) handles points nl and nl+8.
__global__ void __launch_bounds__(512, 4)
match_fused(const u64* __restrict__ Lp, const u64* __restrict__ bs,
            const int2* __restrict__ edges, int* __restrict__ part) {
    __shared__ u64 Ll[3][CW][65];                   // 43.7 KB (pad 65 vs 64)
    __shared__ u64 qsh[3][TN][CW];                  // 10.5 KB
    __shared__ u64 bsP[TN][BS_W64 + 1];             // 20.6 KB (pad 161)

    int chunk = blockIdx.x;                         // 0..27
    int n0 = blockIdx.y * TN;
    int t = threadIdx.x;
    int lane = t & 63;
    int wave = t >> 6;                              // 0..7
    int cw0 = chunk * CW;

    // ---- Phase 1a: L chunk, transposed, coalesced (12 passes of 16 c-rows) ----
    #pragma unroll
    for (int pass = 0; pass < 12; ++pass) {
        int plane = pass >> 2;
        int c = ((pass & 3) << 4) + (t >> 5);       // 16 c-rows per pass
        int w = t & 31;
        if (w < CW)
            Ll[plane][w][c] = Lp[(size_t)plane * LSTRIDE + (size_t)c * W64 + cw0 + w];
    }
    // ---- Phase 1b: 16 point bitsets, coalesced ----
    for (int idx = t; idx < TN * BS_W64; idx += 512) {
        int p = idx / BS_W64, w = idx - p * BS_W64;
        bsP[p][w] = bs[(size_t)(n0 + p) * BS_W64 + w];
    }
    __syncthreads();

    // ---- Phase 2: build Q planes via ballots ----
    {
        int e0 = chunk * (CW * 64) + lane;
        int2 ei = edges[min(e0, N_EDGES - 1)];
        for (int word = 0; word < CW; ++word) {
            int e = e0 + word * 64;
            int2 cur = ei;
            if (word < CW - 1) ei = edges[min(e + 64, N_EDGES - 1)];
            u64 padm = ~__ballot(e < N_EDGES);
            u64 wa0 = bsP[wave][cur.x >> 6];
            u64 wb0 = bsP[wave][cur.y >> 6];
            u64 wa1 = bsP[wave + 8][cur.x >> 6];
            u64 wb1 = bsP[wave + 8][cur.y >> 6];
            u64 A0 = __ballot((wa0 >> (cur.x & 63)) & 1);
            u64 B0 = __ballot((wb0 >> (cur.y & 63)) & 1);
            u64 A1 = __ballot((wa1 >> (cur.x & 63)) & 1);
            u64 B1 = __ballot((wb1 >> (cur.y & 63)) & 1);
            if (lane == 0) {
                qsh[0][wave][word]     = (~B0) | padm;
                qsh[1][wave][word]     = (A0 ^ B0) | padm;
                qsh[2][wave][word]     = (A0 & B0) | padm;
                qsh[0][wave + 8][word] = (~B1) | padm;
                qsh[1][wave + 8][word] = (A1 ^ B1) | padm;
                qsh[2][wave + 8][word] = (A1 & B1) | padm;
            }
        }
    }
    __syncthreads();

    // ---- Phase 3: popcount ----
    int c  = lane;
    int nl = wave;
    int cnt0 = 0, cnt1 = 0;
    #pragma unroll
    for (int w = 0; w < CW; w += 2) {
        u64 l0a = Ll[0][w][c], l0b = Ll[0][w + 1][c];
        u64 l1a = Ll[1][w][c], l1b = Ll[1][w + 1][c];
        u64 l2a = Ll[2][w][c], l2b = Ll[2][w + 1][c];
        u64v2 a0 = *(const u64v2*)&qsh[0][nl][w];
        u64v2 a1 = *(const u64v2*)&qsh[1][nl][w];
        u64v2 a2 = *(const u64v2*)&qsh[2][nl][w];
        cnt0 += __popcll((l0a ^ a0.x) | (l1a ^ a1.x) | (l2a ^ a2.x));
        cnt0 += __popcll((l0b ^ a0.y) | (l1b ^ a1.y) | (l2b ^ a2.y));
        u64v2 b0 = *(const u64v2*)&qsh[0][nl + 8][w];
        u64v2 b1 = *(const u64v2*)&qsh[1][nl + 8][w];
        u64v2 b2 = *(const u64v2*)&qsh[2][nl + 8][w];
        cnt1 += __popcll((l0a ^ b0.x) | (l1a ^ b1.x) | (l2a ^ b2.x));
        cnt1 += __popcll((l0b ^ b0.y) | (l1b ^ b1.y) | (l2b ^ b2.y));
    }
    part[((size_t)chunk * N_PTS + n0 + nl) * N_CMP + c]     = cnt0;
    part[((size_t)chunk * N_PTS + n0 + nl + 8) * N_CMP + c] = cnt1;
}

// ---------------- Kernel D1: sum chunks, energy = EBITS - mismatches, block min ----------------
__global__ void reduce1(const int* __restrict__ part, int* __restrict__ energy,
                        int* __restrict__ blockmin) {
    int t = blockIdx.x * 256 + threadIdx.x;
    int s = 0;
    #pragma unroll
    for (int ch = 0; ch < NCHUNK; ++ch) s += part[ch * (N_PTS * N_CMP) + t];
    int e = EBITS - s;
    energy[t] = e;
    int m = e;
    for (int off = 32; off; off >>= 1) m = min(m, __shfl_down(m, off, 64));
    __shared__ int wm[4];
    if ((threadIdx.x & 63) == 0) wm[threadIdx.x >> 6] = m;
    __syncthreads();
    if (threadIdx.x == 0) blockmin[blockIdx.x] = min(min(wm[0], wm[1]), min(wm[2], wm[3]));
}

// ---------------- Kernel D2: global min (redone per block) + subtract ----------------
__global__ void subk(const int* __restrict__ energy, const int* __restrict__ blockmin,
                     float* __restrict__ out) {
    __shared__ int wm[4];
    __shared__ int ms;
    int t = threadIdx.x;
    int m = t < 128 ? blockmin[t] : 0x7fffffff;
    for (int off = 32; off; off >>= 1) m = min(m, __shfl_down(m, off, 64));
    if ((t & 63) == 0) wm[t >> 6] = m;
    __syncthreads();
    if (t == 0) ms = min(wm[0], wm[1]);
    __syncthreads();
    int mv = ms;
    int i = blockIdx.x * 256 + t;
    int4 e = ((const int4*)energy)[i];
    ((float4*)out)[i] = make_float4((float)(e.x - mv), (float)(e.y - mv),
                                    (float)(e.z - mv), (float)(e.w - mv));
}

extern "C" void kernel_launch(void* const* d_in, const int* in_sizes, int n_in,
                              void* d_out, int out_size, void* d_ws, size_t ws_size,
                              hipStream_t stream) {
    const int*   act   = (const int*)d_in[0];       // 512 x 10000
    const float* BL    = (const float*)d_in[1];     // 64 x 250000
    const int2*  edges = (const int2*)d_in[2];      // 50000 x 2
    float* out = (float*)d_out;

    u64* Lp = (u64*)d_ws;                           // 3*64*784 u64 = 1.20 MB
    u64* bsv = Lp + 3 * (size_t)LSTRIDE;            // 512*160  u64 = 0.66 MB
    int* part     = (int*)(bsv + (size_t)N_PTS * BS_W64); // 28*32768 int = 3.67 MB
    int* energy   = part + NCHUNK * N_PTS * N_CMP;  // 32768 int
    int* blockmin = energy + N_PTS * N_CMP;         // 128 int

    build_L     <<<dim3(EBITS / 256, N_CMP), 256, 0, stream>>>(BL, Lp);
    build_bitset<<<N_PTS, 256, 0, stream>>>(act, bsv);
    match_fused <<<dim3(NCHUNK, N_PTS / TN), 512, 0, stream>>>(Lp, bsv, edges, part);
    reduce1     <<<N_PTS * N_CMP / 256, 256, 0, stream>>>(part, energy, blockmin);
    subk        <<<N_PTS * N_CMP / 1024, 256, 0, stream>>>(energy, blockmin, out);
}

// Round 5
// 49.670 us; speedup vs baseline: 2.5970x; 1.5477x over previous
//
#include <hip/hip_runtime.h>
#include <stdint.h>

#define N_PTS   512
#define N_NODES 10000
#define N_EDGES 50000
#define N_CMP   64
#define W64     784             // u64 words per bit-plane row; 784*64 = 50176
#define EBITS   (W64 * 64)      // 50176
#define LSTRIDE (N_CMP * W64)   // per-plane stride, L
#define NCHUNK  49
#define CW      (W64 / NCHUNK)  // 16 words = 1024 edges per chunk
#define TN      16              // points per block (fixed by u16 bsT)
#define BST_ROW 10016           // padded node count (16B-aligned rows)

typedef unsigned long long u64;

// ---------------- Kernel A: learned-side planes la/lb/tZ (planar) ----------------
// tl in {0..4} from one-hot planes 1..4. la=bit1(tl-1)=p3|p4, lb=bit0(tl-1)=p2|p4,
// tZ=(tl==0)=~(p1|p2|p3|p4). Pad e>=N_EDGES -> tZ=1 (always mismatch). 
__global__ void build_L(const float* __restrict__ BL, u64* __restrict__ Lp) {
    int c = blockIdx.y;
    int e = blockIdx.x * 256 + threadIdx.x;
    int lane = threadIdx.x & 63;
    int la = 0, lb = 0, tz = 1;
    if (e < N_EDGES) {
        size_t base = (size_t)c * (5 * N_EDGES) + e;
        bool p1 = BL[base + 1 * N_EDGES] != 0.f;
        bool p2 = BL[base + 2 * N_EDGES] != 0.f;
        bool p3 = BL[base + 3 * N_EDGES] != 0.f;
        bool p4 = BL[base + 4 * N_EDGES] != 0.f;
        la = p3 | p4;
        lb = p2 | p4;
        tz = !(p1 | p2 | p3 | p4);
    }
    u64 bla = __ballot(la);
    u64 blb = __ballot(lb);
    u64 btz = __ballot(tz);
    if (lane == 0) {
        size_t o = (size_t)c * W64 + (e >> 6);
        Lp[o] = bla; Lp[LSTRIDE + o] = blb; Lp[2 * LSTRIDE + o] = btz;
    }
}

// ---------------- Kernel B: transposed bitsets bsT[group][node] u16 ----------------
// bit p of bsT[g][node] = act[g*16+p][node] != 0. Coalesced reads/writes.
__global__ void build_bsT(const int* __restrict__ act, uint16_t* __restrict__ bsT) {
    int node = blockIdx.x * 256 + threadIdx.x;
    int g = blockIdx.y;
    if (node < N_NODES) {
        uint32_t m = 0;
        #pragma unroll
        for (int p = 0; p < TN; ++p)
            m |= (act[(size_t)(g * TN + p) * N_NODES + node] != 0 ? 1u : 0u) << p;
        bsT[(size_t)g * BST_ROW + node] = (uint16_t)m;
    }
}

// ---------------- Kernel C (fused): in-register Q ballots + mismatch popcount ----------------
// Block (chunk, group): 512 thr = 8 waves. Wave owns points (wave, wave+8).
// Per word: 1 coalesced edge load, 2 u16 LDS gathers, 4 ballots (A/B raw planes,
// consumed in-register), 3 b64 L reads (lanes=c), 2 popcount-accumulates.
__global__ void __launch_bounds__(512, 6)
match_fused(const u64* __restrict__ Lp, const uint16_t* __restrict__ bsT,
            const int2* __restrict__ edges, int* __restrict__ part) {
    __shared__ u64 Ll[3][CW][65];                   // 24.96 KB (pad 65)
    __shared__ uint16_t bsTl[BST_ROW];              // 20.03 KB

    int chunk = blockIdx.x;                         // 0..48
    int g = blockIdx.y;                             // 0..31
    int n0 = g * TN;
    int t = threadIdx.x;
    int lane = t & 63;
    int wave = t >> 6;                              // 0..7
    int cw0 = chunk * CW;

    // Stage L transposed: 192 rows (plane,c) x 16 words, coalesced 128B segments.
    {
        int w = t & 15;
        #pragma unroll
        for (int pass = 0; pass < 6; ++pass) {
            int r = pass * 32 + (t >> 4);           // 0..191
            int plane = r >> 6, c = r & 63;
            Ll[plane][w][c] = Lp[(size_t)plane * LSTRIDE + (size_t)c * W64 + cw0 + w];
        }
    }
    // Stage bsT row: 20032 B as 1252 uint4, coalesced.
    {
        const uint4* src = (const uint4*)(bsT + (size_t)g * BST_ROW);
        uint4* dst = (uint4*)bsTl;
        for (int idx = t; idx < BST_ROW / 8; idx += 512) dst[idx] = src[idx];
    }
    __syncthreads();

    int e0 = chunk * (CW * 64) + lane;
    int2 ep = edges[min(e0, N_EDGES - 1)];
    int cnt0 = 0, cnt1 = 0;
    #pragma unroll
    for (int w = 0; w < CW; ++w) {
        int2 cur = ep;
        if (w < CW - 1) ep = edges[min(e0 + (w + 1) * 64, N_EDGES - 1)];
        uint32_t a16 = bsTl[cur.x];
        uint32_t b16 = bsTl[cur.y];
        u64 A0 = __ballot((a16 >> wave) & 1);
        u64 B0 = __ballot((b16 >> wave) & 1);
        u64 A1 = __ballot((a16 >> (wave + 8)) & 1);
        u64 B1 = __ballot((b16 >> (wave + 8)) & 1);
        u64 la = Ll[0][w][lane];
        u64 lb = Ll[1][w][lane];
        u64 tz = Ll[2][w][lane];
        cnt0 += __popcll(tz | (la ^ A0) | (lb ^ B0));
        cnt1 += __popcll(tz | (la ^ A1) | (lb ^ B1));
    }
    part[((size_t)chunk * N_PTS + n0 + wave) * N_CMP + lane]     = cnt0;
    part[((size_t)chunk * N_PTS + n0 + wave + 8) * N_CMP + lane] = cnt1;
}

// ---------------- Kernel D1: sum chunks, energy = EBITS - mismatches, block min ----------------
__global__ void reduce1(const int* __restrict__ part, int* __restrict__ energy,
                        int* __restrict__ blockmin) {
    int t = blockIdx.x * 256 + threadIdx.x;
    int s = 0;
    #pragma unroll 7
    for (int ch = 0; ch < NCHUNK; ++ch) s += part[ch * (N_PTS * N_CMP) + t];
    int e = EBITS - s;
    energy[t] = e;
    int m = e;
    for (int off = 32; off; off >>= 1) m = min(m, __shfl_down(m, off, 64));
    __shared__ int wm[4];
    if ((threadIdx.x & 63) == 0) wm[threadIdx.x >> 6] = m;
    __syncthreads();
    if (threadIdx.x == 0) blockmin[blockIdx.x] = min(min(wm[0], wm[1]), min(wm[2], wm[3]));
}

// ---------------- Kernel D2: global min (redone per block) + subtract ----------------
__global__ void subk(const int* __restrict__ energy, const int* __restrict__ blockmin,
                     float* __restrict__ out) {
    __shared__ int wm[4];
    __shared__ int ms;
    int t = threadIdx.x;
    int m = t < 128 ? blockmin[t] : 0x7fffffff;
    for (int off = 32; off; off >>= 1) m = min(m, __shfl_down(m, off, 64));
    if ((t & 63) == 0) wm[t >> 6] = m;
    __syncthreads();
    if (t == 0) ms = min(wm[0], wm[1]);
    __syncthreads();
    int mv = ms;
    int i = blockIdx.x * 256 + t;
    int4 e = ((const int4*)energy)[i];
    ((float4*)out)[i] = make_float4((float)(e.x - mv), (float)(e.y - mv),
                                    (float)(e.z - mv), (float)(e.w - mv));
}

extern "C" void kernel_launch(void* const* d_in, const int* in_sizes, int n_in,
                              void* d_out, int out_size, void* d_ws, size_t ws_size,
                              hipStream_t stream) {
    const int*   act   = (const int*)d_in[0];       // 512 x 10000
    const float* BL    = (const float*)d_in[1];     // 64 x 250000
    const int2*  edges = (const int2*)d_in[2];      // 50000 x 2
    float* out = (float*)d_out;

    u64* Lp = (u64*)d_ws;                           // 3*64*784 u64 = 1.204 MB
    uint16_t* bsT = (uint16_t*)(Lp + 3 * (size_t)LSTRIDE);  // 32*10016 u16 = 641 KB
    int* part     = (int*)(bsT + 32 * (size_t)BST_ROW);     // 49*32768 int = 6.42 MB
    int* energy   = part + NCHUNK * N_PTS * N_CMP;  // 32768 int
    int* blockmin = energy + N_PTS * N_CMP;         // 128 int

    build_L     <<<dim3(EBITS / 256, N_CMP), 256, 0, stream>>>(BL, Lp);
    build_bsT   <<<dim3((N_NODES + 255) / 256, N_PTS / TN), 256, 0, stream>>>(act, bsT);
    match_fused <<<dim3(NCHUNK, N_PTS / TN), 512, 0, stream>>>(Lp, bsT, edges, part);
    reduce1     <<<N_PTS * N_CMP / 256, 256, 0, stream>>>(part, energy, blockmin);
    subk        <<<N_PTS * N_CMP / 1024, 256, 0, stream>>>(energy, blockmin, out);
}

// Round 6
// 41.669 us; speedup vs baseline: 3.0956x; 1.1920x over previous
//
#include <hip/hip_runtime.h>
#include <stdint.h>

#define N_PTS   512
#define N_NODES 10000
#define N_EDGES 50000
#define N_CMP   64
#define W64     784             // u64 words per bit-plane row; 784*64 = 50176
#define EBITS   (W64 * 64)      // 50176
#define LSTRIDE (N_CMP * W64)   // per-plane stride, L
#define NCHUNK  49
#define CW      16              // words per chunk = 1024 edges
#define TN      16              // points per group (u16 bsT)
#define BST_ROW 10016           // padded node count (16B-aligned rows)
#define NB_BST  ((N_NODES + 255) / 256)   // 40 node-blocks per group
#define NBLK_L  (NCHUNK * N_CMP)          // 3136 build_L blocks

typedef unsigned long long u64;

// ---------------- Kernel A (fused): build_L + build_bsT ----------------
// build_L part: planes la=p3|p4, lb=p2|p4, tz=p0 (one-hot => tl==0 <=> p0).
// float4 loads (16B/lane), nibble-pack via LDS, 48 packer threads/block.
// Pad e>=N_EDGES -> tz=1 (always mismatch; contributes 0 matches).
__global__ void build_all(const int* __restrict__ act, const float* __restrict__ BL,
                          u64* __restrict__ Lp, uint16_t* __restrict__ bsT) {
    int bid = blockIdx.x;
    int t = threadIdx.x;
    if (bid < NBLK_L) {
        __shared__ uint16_t sh[256];
        int c = bid / NCHUNK, bx = bid % NCHUNK;    // c row, 1024-edge block
        int e0 = bx * 1024 + 4 * t;
        int nla = 0, nlb = 0, ntz = 0xF;
        if (e0 < N_EDGES) {                          // N_EDGES%4==0: all-or-none
            const float* base = BL + (size_t)c * (5 * N_EDGES) + e0;
            float4 p0 = *(const float4*)(base);
            float4 p2 = *(const float4*)(base + 2 * N_EDGES);
            float4 p3 = *(const float4*)(base + 3 * N_EDGES);
            float4 p4 = *(const float4*)(base + 4 * N_EDGES);
            #define B_(f) ((f) != 0.f ? 1 : 0)
            nla = (B_(p3.x) | B_(p4.x)) | ((B_(p3.y) | B_(p4.y)) << 1)
                | ((B_(p3.z) | B_(p4.z)) << 2) | ((B_(p3.w) | B_(p4.w)) << 3);
            nlb = (B_(p2.x) | B_(p4.x)) | ((B_(p2.y) | B_(p4.y)) << 1)
                | ((B_(p2.z) | B_(p4.z)) << 2) | ((B_(p2.w) | B_(p4.w)) << 3);
            ntz = B_(p0.x) | (B_(p0.y) << 1) | (B_(p0.z) << 2) | (B_(p0.w) << 3);
            #undef B_
        }
        sh[t] = (uint16_t)(nla | (nlb << 4) | (ntz << 8));
        __syncthreads();
        if (t < 48) {                                // plane p, word w of 16
            int p = t >> 4, w = t & 15;
            const u64* v = (const u64*)sh + w * 4;   // 4 u64 = 16 u16 nibble-sources
            u64 word = 0;
            #pragma unroll
            for (int i = 0; i < 4; ++i) {
                u64 x = v[i];
                #pragma unroll
                for (int kk = 0; kk < 4; ++kk)
                    word |= ((x >> (16 * kk + 4 * p)) & 0xFULL) << (4 * (i * 4 + kk));
            }
            Lp[(size_t)p * LSTRIDE + (size_t)c * W64 + bx * 16 + w] = word;
        }
    } else {
        // transposed bitsets: bit p of bsT[g][node] = act[g*16+p][node] != 0
        int rem = bid - NBLK_L;
        int g = rem / NB_BST, nb = rem % NB_BST;
        int node = nb * 256 + t;
        if (node < N_NODES) {
            uint32_t m = 0;
            #pragma unroll
            for (int p = 0; p < TN; ++p)
                m |= (act[(size_t)(g * TN + p) * N_NODES + node] != 0 ? 1u : 0u) << p;
            bsT[(size_t)g * BST_ROW + node] = (uint16_t)m;
        }
    }
}

// ---------------- Kernel C (fused): in-register Q ballots + mismatch popcount ----------------
// Block (chunk, group): 512 thr = 8 waves; wave owns points (wave, wave+8).
// All inner-loop memory ops hit LDS: edges (staged), bsT row (staged), L (staged transposed).
__global__ void __launch_bounds__(512, 6)
match_fused(const u64* __restrict__ Lp, const uint16_t* __restrict__ bsT,
            const int2* __restrict__ edges, uint32_t* __restrict__ part32) {
    __shared__ u64 Ll[3][CW][65];                   // 24.96 KB (pad 65)
    __shared__ uint16_t bsTl[BST_ROW];              // 20.03 KB
    __shared__ int2 edgl[CW * 64];                  // 8 KB

    int chunk = blockIdx.x;                         // 0..48
    int g = blockIdx.y;                             // 0..31
    int t = threadIdx.x;
    int lane = t & 63;
    int wave = t >> 6;                              // 0..7
    int cw0 = chunk * CW;

    // Stage L transposed: 192 rows (plane,c) x 16 words, coalesced 128B segments.
    {
        int w = t & 15;
        #pragma unroll
        for (int pass = 0; pass < 6; ++pass) {
            int r = pass * 32 + (t >> 4);           // 0..191
            int plane = r >> 6, c = r & 63;
            Ll[plane][w][c] = Lp[(size_t)plane * LSTRIDE + (size_t)c * W64 + cw0 + w];
        }
    }
    // Stage bsT row: 20032 B as 1252 uint4, coalesced.
    {
        const uint4* src = (const uint4*)(bsT + (size_t)g * BST_ROW);
        uint4* dst = (uint4*)bsTl;
        for (int idx = t; idx < BST_ROW / 8; idx += 512) dst[idx] = src[idx];
    }
    // Stage edge chunk: 1024 int2, clamped tail (pads are tz-masked anyway).
    {
        int e = chunk * 1024 + t;
        edgl[t]       = edges[min(e, N_EDGES - 1)];
        edgl[t + 512] = edges[min(e + 512, N_EDGES - 1)];
    }
    __syncthreads();

    int cnt0 = 0, cnt1 = 0;
    #pragma unroll
    for (int w = 0; w < CW; ++w) {
        int2 cur = edgl[w * 64 + lane];
        uint32_t a16 = bsTl[cur.x];
        uint32_t b16 = bsTl[cur.y];
        u64 A0 = __ballot((a16 >> wave) & 1);
        u64 B0 = __ballot((b16 >> wave) & 1);
        u64 A1 = __ballot((a16 >> (wave + 8)) & 1);
        u64 B1 = __ballot((b16 >> (wave + 8)) & 1);
        u64 la = Ll[0][w][lane];
        u64 lb = Ll[1][w][lane];
        u64 tz = Ll[2][w][lane];
        cnt0 += __popcll(tz | (la ^ A0) | (lb ^ B0));
        cnt1 += __popcll(tz | (la ^ A1) | (lb ^ B1));
    }
    part32[(((size_t)chunk * 32 + g) * 8 + wave) * 64 + lane] =
        (uint32_t)cnt0 | ((uint32_t)cnt1 << 16);
}

// ---------------- Kernel D1: sum chunks, energy = EBITS - mismatches, block min ----------------
__global__ void reduce1(const uint32_t* __restrict__ part32, int* __restrict__ energy,
                        int* __restrict__ blockmin) {
    int t = blockIdx.x * 256 + threadIdx.x;         // (n,c)
    int c = t & 63, n = t >> 6;
    int g = n >> 4, p = n & 15;
    int wv = p & 7, hi = (p >> 3) * 16;
    int s = 0;
    #pragma unroll 7
    for (int ch = 0; ch < NCHUNK; ++ch)
        s += (part32[(((size_t)ch * 32 + g) * 8 + wv) * 64 + c] >> hi) & 0xFFFF;
    int e = EBITS - s;
    energy[t] = e;
    int m = e;
    for (int off = 32; off; off >>= 1) m = min(m, __shfl_down(m, off, 64));
    __shared__ int wm[4];
    if ((threadIdx.x & 63) == 0) wm[threadIdx.x >> 6] = m;
    __syncthreads();
    if (threadIdx.x == 0) blockmin[blockIdx.x] = min(min(wm[0], wm[1]), min(wm[2], wm[3]));
}

// ---------------- Kernel D2: global min (redone per block) + subtract ----------------
__global__ void subk(const int* __restrict__ energy, const int* __restrict__ blockmin,
                     float* __restrict__ out) {
    __shared__ int wm[4];
    __shared__ int ms;
    int t = threadIdx.x;
    int m = t < 128 ? blockmin[t] : 0x7fffffff;
    for (int off = 32; off; off >>= 1) m = min(m, __shfl_down(m, off, 64));
    if ((t & 63) == 0) wm[t >> 6] = m;
    __syncthreads();
    if (t == 0) ms = min(wm[0], wm[1]);
    __syncthreads();
    int mv = ms;
    int i = blockIdx.x * 256 + t;
    int4 e = ((const int4*)energy)[i];
    ((float4*)out)[i] = make_float4((float)(e.x - mv), (float)(e.y - mv),
                                    (float)(e.z - mv), (float)(e.w - mv));
}

extern "C" void kernel_launch(void* const* d_in, const int* in_sizes, int n_in,
                              void* d_out, int out_size, void* d_ws, size_t ws_size,
                              hipStream_t stream) {
    const int*   act   = (const int*)d_in[0];       // 512 x 10000
    const float* BL    = (const float*)d_in[1];     // 64 x 250000
    const int2*  edges = (const int2*)d_in[2];      // 50000 x 2
    float* out = (float*)d_out;

    u64* Lp = (u64*)d_ws;                                   // 3*64*784 u64 = 1.204 MB
    uint16_t* bsT = (uint16_t*)(Lp + 3 * (size_t)LSTRIDE);  // 32*10016 u16 = 641 KB
    uint32_t* part32 = (uint32_t*)(bsT + 32 * (size_t)BST_ROW); // 49*32*8*64 u32 = 3.21 MB
    int* energy   = (int*)(part32 + (size_t)NCHUNK * N_PTS / 2 * N_CMP); // 32768 int
    int* blockmin = energy + N_PTS * N_CMP;                 // 128 int

    build_all   <<<NBLK_L + (N_PTS / TN) * NB_BST, 256, 0, stream>>>(act, BL, Lp, bsT);
    match_fused <<<dim3(NCHUNK, N_PTS / TN), 512, 0, stream>>>(Lp, bsT, edges, part32);
    reduce1     <<<N_PTS * N_CMP / 256, 256, 0, stream>>>(part32, energy, blockmin);
    subk        <<<N_PTS * N_CMP / 1024, 256, 0, stream>>>(energy, blockmin, out);
}